// Round 3
// baseline (133.958 us; speedup 1.0000x reference)
//
#include <hip/hip_runtime.h>
#include <stdint.h>

#define S_LEN 2048
#define NB 2
#define NH 16
#define DK 64
#define DM 1024
#define QK_SCALE 0.125f
#define NEG_BIG -1e30f

typedef __attribute__((ext_vector_type(8))) short bf16x8;
typedef __attribute__((ext_vector_type(4))) float f32x4;

static __device__ __forceinline__ f32x4 mfma16(bf16x8 a, bf16x8 b, f32x4 c) {
    return __builtin_amdgcn_mfma_f32_16x16x32_bf16(a, b, c, 0, 0, 0);
}

// async global->LDS, 16B per lane; dst is wave-uniform base, HW adds lane*16
static __device__ __forceinline__ void gload_lds16(const void* g, void* l) {
    __builtin_amdgcn_global_load_lds((const __attribute__((address_space(1))) void*)g,
                                     (__attribute__((address_space(3))) void*)l,
                                     16, 0, 0);
}

// fp32 -> bf16 bits, RNE (inputs always finite here)
static __device__ __forceinline__ unsigned short f2bf(float x) {
    unsigned int u = __float_as_uint(x);
    u += 0x7fffu + ((u >> 16) & 1u);
    return (unsigned short)(u >> 16);
}

// ---------------- conversion: fp32 -> bf16, 7 tensors in one launch -------
struct CvtArgs {
    const float* src[7];
    unsigned short* dst[7];
    int n8[7];
};

__global__ __launch_bounds__(256) void cvt_f32_bf16(CvtArgs a) {
    const int t = blockIdx.y;
    const float* __restrict__ src = a.src[t];
    unsigned short* __restrict__ dst = a.dst[t];
    const int n8 = a.n8[t];
    const int stride = gridDim.x * blockDim.x;
    for (int i = blockIdx.x * blockDim.x + threadIdx.x; i < n8; i += stride) {
        float4 v0 = ((const float4*)src)[(size_t)i * 2];
        float4 v1 = ((const float4*)src)[(size_t)i * 2 + 1];
        union { bf16x8 v; unsigned short h[8]; } u;
        u.h[0] = f2bf(v0.x); u.h[1] = f2bf(v0.y); u.h[2] = f2bf(v0.z); u.h[3] = f2bf(v0.w);
        u.h[4] = f2bf(v1.x); u.h[5] = f2bf(v1.y); u.h[6] = f2bf(v1.z); u.h[7] = f2bf(v1.w);
        ((bf16x8*)dst)[i] = u.v;
    }
}

// ================= 256x256 8-phase QKV GEMM (T2+T3+T4+T5) ==================
// 512 threads = 8 waves (2M x 4N). Per-wave output 128x64 = acc[8][4].
// LDS 128KB: [A0 32K][B0 32K][A1 32K][B1 32K], double-buffered per K-tile(64).
// Bank-conflict fix: chunk ^= (row&7) involution; linear gload_lds dest with
// pre-swizzled GLOBAL source + swizzled ds_read (both-sides rule).
// Schedule/K-tile: issue 8 prefetch loads (t+1 -> buf^1), then 4 phases of
// {ds_read subtile, s_barrier, setprio(1), 16 MFMA, setprio(0), s_barrier},
// then __syncthreads() (vmcnt(0) drain hidden under the 4 phases of compute).
__global__ __launch_bounds__(512, 2) void gemm_qkv8(
    const unsigned short* __restrict__ Xq, const unsigned short* __restrict__ Xk,
    const unsigned short* __restrict__ Xv,
    const unsigned short* __restrict__ Wq, const unsigned short* __restrict__ Wk,
    const unsigned short* __restrict__ Wv,
    const float* __restrict__ bq, const float* __restrict__ bk, const float* __restrict__ bv,
    unsigned short* __restrict__ Qo, unsigned short* __restrict__ Ko,
    unsigned short* __restrict__ Vt)
{
    __shared__ unsigned short lds[65536];   // 128 KiB

    const int tid = threadIdx.x, wid = tid >> 6, lane = tid & 63;
    const int wm = wid >> 2, wn = wid & 3;
    const int fr = lane & 15, fg = lane >> 4;
    const int z = blockIdx.z;
    const int m0 = blockIdx.y * 256, n0 = blockIdx.x * 256;

    const unsigned short* A = (z == 0) ? Xq : ((z == 1) ? Xk : Xv);
    const unsigned short* W = (z == 0) ? Wq : ((z == 1) ? Wk : Wv);
    const float* bias = (z == 0) ? bq : ((z == 1) ? bk : bv);

    // staging: inst i covers rows i*64 + wid*8 + (lane>>3); source col chunk
    // pre-swizzled by ^(row&7) = ^(lane>>3) so the LINEAR LDS dest holds the
    // swizzled layout.
    const int srow = wid * 8 + (lane >> 3);
    const int scol = ((lane & 7) ^ (lane >> 3)) * 8;
    const unsigned short* pA = A + (size_t)(m0 + srow) * DM + scol;
    const unsigned short* pW = W + (size_t)(n0 + srow) * DM + scol;

    // ds_read offsets (elems). row&7 == fr&7 for all fragments.
    const int base_a = (wm * 128 + fr) * 64;
    const int base_b = (wn * 64 + fr) * 64;
    const int ck0 = ((0 * 4 + fg) ^ (fr & 7)) * 8;   // ks=0 chunk byte offset/2
    const int ck1 = ((1 * 4 + fg) ^ (fr & 7)) * 8;   // ks=1

    f32x4 acc[8][4] = {};

    // prologue: stage K-tile 0 into buf0
    {
        unsigned short* dA = lds + wid * 512;
        unsigned short* dB = lds + 16384 + wid * 512;
        #pragma unroll
        for (int i = 0; i < 4; ++i) {
            gload_lds16(pA + (size_t)i * 64 * DM, dA + i * 4096);
            gload_lds16(pW + (size_t)i * 64 * DM, dB + i * 4096);
        }
    }
    __syncthreads();

    for (int t = 0; t < 16; ++t) {
        const int c = t & 1;
        // prefetch tile t+1 into the other buffer (reads of it drained at the
        // previous __syncthreads)
        if (t + 1 < 16) {
            const int k0 = (t + 1) * 64;
            unsigned short* dA = lds + (c ^ 1) * 32768 + wid * 512;
            unsigned short* dB = lds + (c ^ 1) * 32768 + 16384 + wid * 512;
            #pragma unroll
            for (int i = 0; i < 4; ++i) {
                gload_lds16(pA + (size_t)i * 64 * DM + k0, dA + i * 4096);
                gload_lds16(pW + (size_t)i * 64 * DM + k0, dB + i * 4096);
            }
        }
        const unsigned short* sA = lds + c * 32768;
        const unsigned short* sB = sA + 16384;

        bf16x8 a0, a1, a2, a3, a0k, a1k, a2k, a3k;
        bf16x8 b0, b1, b2, b3, b0k, b1k, b2k, b3k;

        // ---- phase 0: A mf0-3 (both ksteps) + B nf0-1; MFMA m0-3 x n0-1
        a0  = *(const bf16x8*)(sA + base_a + 0 * 1024 + ck0);
        a1  = *(const bf16x8*)(sA + base_a + 1 * 1024 + ck0);
        a2  = *(const bf16x8*)(sA + base_a + 2 * 1024 + ck0);
        a3  = *(const bf16x8*)(sA + base_a + 3 * 1024 + ck0);
        a0k = *(const bf16x8*)(sA + base_a + 0 * 1024 + ck1);
        a1k = *(const bf16x8*)(sA + base_a + 1 * 1024 + ck1);
        a2k = *(const bf16x8*)(sA + base_a + 2 * 1024 + ck1);
        a3k = *(const bf16x8*)(sA + base_a + 3 * 1024 + ck1);
        b0  = *(const bf16x8*)(sB + base_b + 0 * 1024 + ck0);
        b1  = *(const bf16x8*)(sB + base_b + 1 * 1024 + ck0);
        b0k = *(const bf16x8*)(sB + base_b + 0 * 1024 + ck1);
        b1k = *(const bf16x8*)(sB + base_b + 1 * 1024 + ck1);
        __builtin_amdgcn_s_barrier();
        __builtin_amdgcn_s_setprio(1);
        acc[0][0] = mfma16(a0, b0, acc[0][0]); acc[0][0] = mfma16(a0k, b0k, acc[0][0]);
        acc[0][1] = mfma16(a0, b1, acc[0][1]); acc[0][1] = mfma16(a0k, b1k, acc[0][1]);
        acc[1][0] = mfma16(a1, b0, acc[1][0]); acc[1][0] = mfma16(a1k, b0k, acc[1][0]);
        acc[1][1] = mfma16(a1, b1, acc[1][1]); acc[1][1] = mfma16(a1k, b1k, acc[1][1]);
        acc[2][0] = mfma16(a2, b0, acc[2][0]); acc[2][0] = mfma16(a2k, b0k, acc[2][0]);
        acc[2][1] = mfma16(a2, b1, acc[2][1]); acc[2][1] = mfma16(a2k, b1k, acc[2][1]);
        acc[3][0] = mfma16(a3, b0, acc[3][0]); acc[3][0] = mfma16(a3k, b0k, acc[3][0]);
        acc[3][1] = mfma16(a3, b1, acc[3][1]); acc[3][1] = mfma16(a3k, b1k, acc[3][1]);
        __builtin_amdgcn_s_setprio(0);
        __builtin_amdgcn_s_barrier();

        // ---- phase 1: B nf2-3; MFMA m0-3 x n2-3
        b2  = *(const bf16x8*)(sB + base_b + 2 * 1024 + ck0);
        b3  = *(const bf16x8*)(sB + base_b + 3 * 1024 + ck0);
        b2k = *(const bf16x8*)(sB + base_b + 2 * 1024 + ck1);
        b3k = *(const bf16x8*)(sB + base_b + 3 * 1024 + ck1);
        __builtin_amdgcn_s_barrier();
        __builtin_amdgcn_s_setprio(1);
        acc[0][2] = mfma16(a0, b2, acc[0][2]); acc[0][2] = mfma16(a0k, b2k, acc[0][2]);
        acc[0][3] = mfma16(a0, b3, acc[0][3]); acc[0][3] = mfma16(a0k, b3k, acc[0][3]);
        acc[1][2] = mfma16(a1, b2, acc[1][2]); acc[1][2] = mfma16(a1k, b2k, acc[1][2]);
        acc[1][3] = mfma16(a1, b3, acc[1][3]); acc[1][3] = mfma16(a1k, b3k, acc[1][3]);
        acc[2][2] = mfma16(a2, b2, acc[2][2]); acc[2][2] = mfma16(a2k, b2k, acc[2][2]);
        acc[2][3] = mfma16(a2, b3, acc[2][3]); acc[2][3] = mfma16(a2k, b3k, acc[2][3]);
        acc[3][2] = mfma16(a3, b2, acc[3][2]); acc[3][2] = mfma16(a3k, b2k, acc[3][2]);
        acc[3][3] = mfma16(a3, b3, acc[3][3]); acc[3][3] = mfma16(a3k, b3k, acc[3][3]);
        __builtin_amdgcn_s_setprio(0);
        __builtin_amdgcn_s_barrier();

        // ---- phase 2: A mf4-7; MFMA m4-7 x n0-1
        a0  = *(const bf16x8*)(sA + base_a + 4 * 1024 + ck0);
        a1  = *(const bf16x8*)(sA + base_a + 5 * 1024 + ck0);
        a2  = *(const bf16x8*)(sA + base_a + 6 * 1024 + ck0);
        a3  = *(const bf16x8*)(sA + base_a + 7 * 1024 + ck0);
        a0k = *(const bf16x8*)(sA + base_a + 4 * 1024 + ck1);
        a1k = *(const bf16x8*)(sA + base_a + 5 * 1024 + ck1);
        a2k = *(const bf16x8*)(sA + base_a + 6 * 1024 + ck1);
        a3k = *(const bf16x8*)(sA + base_a + 7 * 1024 + ck1);
        __builtin_amdgcn_s_barrier();
        __builtin_amdgcn_s_setprio(1);
        acc[4][0] = mfma16(a0, b0, acc[4][0]); acc[4][0] = mfma16(a0k, b0k, acc[4][0]);
        acc[4][1] = mfma16(a0, b1, acc[4][1]); acc[4][1] = mfma16(a0k, b1k, acc[4][1]);
        acc[5][0] = mfma16(a1, b0, acc[5][0]); acc[5][0] = mfma16(a1k, b0k, acc[5][0]);
        acc[5][1] = mfma16(a1, b1, acc[5][1]); acc[5][1] = mfma16(a1k, b1k, acc[5][1]);
        acc[6][0] = mfma16(a2, b0, acc[6][0]); acc[6][0] = mfma16(a2k, b0k, acc[6][0]);
        acc[6][1] = mfma16(a2, b1, acc[6][1]); acc[6][1] = mfma16(a2k, b1k, acc[6][1]);
        acc[7][0] = mfma16(a3, b0, acc[7][0]); acc[7][0] = mfma16(a3k, b0k, acc[7][0]);
        acc[7][1] = mfma16(a3, b1, acc[7][1]); acc[7][1] = mfma16(a3k, b1k, acc[7][1]);
        __builtin_amdgcn_s_setprio(0);
        __builtin_amdgcn_s_barrier();

        // ---- phase 3: MFMA m4-7 x n2-3 (no loads)
        __builtin_amdgcn_s_setprio(1);
        acc[4][2] = mfma16(a0, b2, acc[4][2]); acc[4][2] = mfma16(a0k, b2k, acc[4][2]);
        acc[4][3] = mfma16(a0, b3, acc[4][3]); acc[4][3] = mfma16(a0k, b3k, acc[4][3]);
        acc[5][2] = mfma16(a1, b2, acc[5][2]); acc[5][2] = mfma16(a1k, b2k, acc[5][2]);
        acc[5][3] = mfma16(a1, b3, acc[5][3]); acc[5][3] = mfma16(a1k, b3k, acc[5][3]);
        acc[6][2] = mfma16(a2, b2, acc[6][2]); acc[6][2] = mfma16(a2k, b2k, acc[6][2]);
        acc[6][3] = mfma16(a2, b3, acc[6][3]); acc[6][3] = mfma16(a2k, b3k, acc[6][3]);
        acc[7][2] = mfma16(a3, b2, acc[7][2]); acc[7][2] = mfma16(a3k, b2k, acc[7][2]);
        acc[7][3] = mfma16(a3, b3, acc[7][3]); acc[7][3] = mfma16(a3k, b3k, acc[7][3]);
        __builtin_amdgcn_s_setprio(0);

        // tile boundary: drains vmcnt(0) (prefetch landed) + lgkm + barrier.
        // The drain is hidden: issue-to-wait distance = 4 phases of compute.
        __syncthreads();
    }

    // epilogue
    const unsigned short* Oh = nullptr;  (void)Oh;
    unsigned short* Ohw = (z == 0) ? Qo : Ko;
    #pragma unroll
    for (int nf = 0; nf < 4; ++nf) {
        const int col = n0 + wn * 64 + nf * 16 + fr;
        const float bb = bias[col];
        const int h = col >> 6, dd = col & (DK - 1);
        #pragma unroll
        for (int mf = 0; mf < 8; ++mf) {
            #pragma unroll
            for (int r = 0; r < 4; ++r) {
                const int row = m0 + wm * 128 + mf * 16 + fg * 4 + r;
                const int b = row >> 11, s = row & (S_LEN - 1);
                const float val = acc[mf][nf][r] + bb;
                if (z < 2)
                    Ohw[(((size_t)b * NH + h) * S_LEN + s) * DK + dd] = f2bf(val);
                else
                    Vt[(((size_t)b * NH + h) * DK + dd) * S_LEN + s] = f2bf(val);
            }
        }
    }
}

// ---------------- GEMM core (m97 128^2) for the output projection ----------
static __device__ __forceinline__ void gemm_core_128(
    const unsigned short* __restrict__ A,
    const unsigned short* __restrict__ W,
    unsigned short* sA, unsigned short* sB,
    int K, int m0, int n0, f32x4 acc[4][4])
{
    const int tid = threadIdx.x;
    const int wid = tid >> 6, lane = tid & 63;
    const int wr = wid >> 1, wc = wid & 1;
    const int fr = lane & 15, fg = lane >> 4;
    const int ldr = lane >> 3, ldc = (lane & 7) * 8;

    const unsigned short* pA = A + (size_t)(m0 + ldr) * K + ldc;
    const unsigned short* pW = W + (size_t)(n0 + ldr) * K + ldc;

    for (int k0 = 0; k0 < K; k0 += 64) {
        __syncthreads();
        #pragma unroll
        for (int it = 0; it < 4; ++it) {
            const int rb = wid * 32 + it * 8;
            gload_lds16(pA + (size_t)(rb)*K + k0, sA + rb * 64);
            gload_lds16(pW + (size_t)(rb)*K + k0, sB + rb * 64);
        }
        __syncthreads();
        #pragma unroll
        for (int kf = 0; kf < 2; ++kf) {
            bf16x8 af[4], bfr[4];
            #pragma unroll
            for (int mf = 0; mf < 4; ++mf)
                af[mf] = *(const bf16x8*)(sA + (wr * 64 + mf * 16 + fr) * 64 + kf * 32 + fg * 8);
            #pragma unroll
            for (int nf = 0; nf < 4; ++nf)
                bfr[nf] = *(const bf16x8*)(sB + (wc * 64 + nf * 16 + fr) * 64 + kf * 32 + fg * 8);
            #pragma unroll
            for (int mf = 0; mf < 4; ++mf)
                #pragma unroll
                for (int nf = 0; nf < 4; ++nf)
                    acc[mf][nf] = mfma16(af[mf], bfr[nf], acc[mf][nf]);
        }
    }
}

// ---------------- final output projection: fp32 out + bias -----------------
__global__ __launch_bounds__(256, 2) void gemm_out(
    const unsigned short* __restrict__ A, const unsigned short* __restrict__ W,
    const float* __restrict__ bias, float* __restrict__ out)
{
    __shared__ unsigned short sA[128 * 64];
    __shared__ unsigned short sB[128 * 64];
    const int m0 = blockIdx.y * 128, n0 = blockIdx.x * 128;
    f32x4 acc[4][4] = {};
    gemm_core_128(A, W, sA, sB, DM, m0, n0, acc);
    const int tid = threadIdx.x, wid = tid >> 6, lane = tid & 63;
    const int wr = wid >> 1, wc = wid & 1, fr = lane & 15, fg = lane >> 4;
    #pragma unroll
    for (int nf = 0; nf < 4; ++nf) {
        const int col = n0 + wc * 64 + nf * 16 + fr;
        const float bb = bias[col];
        #pragma unroll
        for (int mf = 0; mf < 4; ++mf) {
            #pragma unroll
            for (int r = 0; r < 4; ++r) {
                const int row = m0 + wr * 64 + mf * 16 + fg * 4 + r;
                out[(size_t)row * DM + col] = acc[mf][nf][r] + bb;
            }
        }
    }
}

// ---------------- banded flash attention ----------------------------------
__global__ __launch_bounds__(256, 2) void attn_kernel(
    const unsigned short* __restrict__ Qb,   // [B,H,S,64]
    const unsigned short* __restrict__ Kb,   // [B,H,S,64]
    const unsigned short* __restrict__ Vt,   // [B,H,64,S]
    unsigned short* __restrict__ Oout)       // [B*S, 1024] token-major
{
    __shared__ unsigned short sK[128 * 64];
    __shared__ unsigned short sV[64 * 128];
    __shared__ unsigned short sP[4][32 * 128];

    const int tid = threadIdx.x, wid = tid >> 6, lane = tid & 63;
    const int fr = lane & 15, fg = lane >> 4;
    const int qt = blockIdx.x, bh = blockIdx.y;
    const int q0 = qt * 128;
    const size_t base = (size_t)bh * (S_LEN * DK);

    bf16x8 qf[2][2];
    #pragma unroll
    for (int mf = 0; mf < 2; ++mf)
        #pragma unroll
        for (int kf = 0; kf < 2; ++kf)
            qf[mf][kf] = *(const bf16x8*)(Qb + base +
                (size_t)(q0 + wid * 32 + mf * 16 + fr) * DK + kf * 32 + fg * 8);

    f32x4 oacc[2][4] = {};
    float m_run[2][4], l_run[2][4];
    #pragma unroll
    for (int mf = 0; mf < 2; ++mf)
        #pragma unroll
        for (int r = 0; r < 4; ++r) { m_run[mf][r] = NEG_BIG; l_run[mf][r] = 0.f; }

    const int t_lo = (qt == 0) ? 1 : 0;
    const int t_hi = (qt == (S_LEN / 128 - 1)) ? 1 : 2;

    for (int t = t_lo; t <= t_hi; ++t) {
        const int kt0 = q0 + (t - 1) * 128;
        __syncthreads();
        {
            const unsigned short* gK = Kb + base + (size_t)kt0 * DK;
            #pragma unroll
            for (int it = 0; it < 4; ++it) {
                const int chunk = wid * 4 + it;
                gload_lds16(gK + chunk * 512 + lane * 8, sK + chunk * 512);
            }
            const unsigned short* gV = Vt + base + kt0;
            #pragma unroll
            for (int it = 0; it < 4; ++it) {
                const int chunk = wid * 4 + it;
                gload_lds16(gV + (size_t)(chunk * 4 + fg) * S_LEN + fr * 8, sV + chunk * 512);
            }
        }
        __syncthreads();

        f32x4 sacc[2][8] = {};
        #pragma unroll
        for (int kf = 0; kf < 2; ++kf) {
            bf16x8 kfr[8];
            #pragma unroll
            for (int nf = 0; nf < 8; ++nf)
                kfr[nf] = *(const bf16x8*)(sK + (nf * 16 + fr) * 64 + kf * 32 + fg * 8);
            #pragma unroll
            for (int mf = 0; mf < 2; ++mf)
                #pragma unroll
                for (int nf = 0; nf < 8; ++nf)
                    sacc[mf][nf] = mfma16(qf[mf][kf], kfr[nf], sacc[mf][nf]);
        }

        const int dt = (t - 1) * 128;
        #pragma unroll
        for (int mf = 0; mf < 2; ++mf) {
            #pragma unroll
            for (int r = 0; r < 4; ++r) {
                const int row = wid * 32 + mf * 16 + fg * 4 + r;
                float mm = NEG_BIG;
                #pragma unroll
                for (int nf = 0; nf < 8; ++nf) {
                    const int col = nf * 16 + fr;
                    const int diff = dt + col - row;
                    float s = sacc[mf][nf][r] * QK_SCALE;
                    s = (diff >= -128 && diff < 128) ? s : NEG_BIG;
                    sacc[mf][nf][r] = s;
                    mm = fmaxf(mm, s);
                }
                #pragma unroll
                for (int d = 1; d < 16; d <<= 1) mm = fmaxf(mm, __shfl_xor(mm, d));
                const float mold = m_run[mf][r];
                const float mn = fmaxf(mold, mm);
                m_run[mf][r] = mn;
                const float alpha = __expf(mold - mn);
                float ps = 0.f;
                #pragma unroll
                for (int nf = 0; nf < 8; ++nf) {
                    const float p = __expf(sacc[mf][nf][r] - mn);
                    ps += p;
                    sP[wid][(mf * 16 + fg * 4 + r) * 128 + nf * 16 + fr] = f2bf(p);
                }
                #pragma unroll
                for (int d = 1; d < 16; d <<= 1) ps += __shfl_xor(ps, d);
                l_run[mf][r] = l_run[mf][r] * alpha + ps;
                #pragma unroll
                for (int nf = 0; nf < 4; ++nf)
                    oacc[mf][nf][r] = oacc[mf][nf][r] * alpha;
            }
        }

        #pragma unroll
        for (int kf = 0; kf < 4; ++kf) {
            bf16x8 pa[2], vb[4];
            #pragma unroll
            for (int mf = 0; mf < 2; ++mf)
                pa[mf] = *(const bf16x8*)(&sP[wid][(mf * 16 + fr) * 128 + kf * 32 + fg * 8]);
            #pragma unroll
            for (int nf = 0; nf < 4; ++nf)
                vb[nf] = *(const bf16x8*)(sV + (nf * 16 + fr) * 128 + kf * 32 + fg * 8);
            #pragma unroll
            for (int mf = 0; mf < 2; ++mf)
                #pragma unroll
                for (int nf = 0; nf < 4; ++nf)
                    oacc[mf][nf] = mfma16(pa[mf], vb[nf], oacc[mf][nf]);
        }
    }

    const int b = bh >> 4, h = bh & 15;
    #pragma unroll
    for (int mf = 0; mf < 2; ++mf) {
        #pragma unroll
        for (int r = 0; r < 4; ++r) {
            const float inv = 1.0f / l_run[mf][r];
            const int token = b * S_LEN + q0 + wid * 32 + mf * 16 + fg * 4 + r;
            #pragma unroll
            for (int nf = 0; nf < 4; ++nf) {
                const int feat = h * 64 + nf * 16 + fr;
                Oout[(size_t)token * DM + feat] = f2bf(oacc[mf][nf][r] * inv);
            }
        }
    }
}

// ---------------------------------------------------------------------------
extern "C" void kernel_launch(void* const* d_in, const int* in_sizes, int n_in,
                              void* d_out, int out_size, void* d_ws, size_t ws_size,
                              hipStream_t stream)
{
    (void)in_sizes; (void)n_in; (void)out_size; (void)ws_size;
    const float* q  = (const float*)d_in[0];
    const float* k  = (const float*)d_in[1];
    const float* v  = (const float*)d_in[2];
    const float* Wq = (const float*)d_in[3];
    const float* bq = (const float*)d_in[4];
    const float* Wk = (const float*)d_in[5];
    const float* bk = (const float*)d_in[6];
    const float* Wv = (const float*)d_in[7];
    const float* bv = (const float*)d_in[8];
    const float* Wo = (const float*)d_in[9];
    const float* bo = (const float*)d_in[10];

    char* ws = (char*)d_ws;
    const size_t MB = 1024 * 1024;
    unsigned short* Xq  = (unsigned short*)(ws + 0 * MB);
    unsigned short* Xk  = (unsigned short*)(ws + 8 * MB);
    unsigned short* Xv  = (unsigned short*)(ws + 16 * MB);
    unsigned short* Qb  = (unsigned short*)(ws + 24 * MB);
    unsigned short* Kb  = (unsigned short*)(ws + 32 * MB);
    unsigned short* Vt  = (unsigned short*)(ws + 40 * MB);
    unsigned short* Wqb = (unsigned short*)(ws + 48 * MB);
    unsigned short* Wkb = (unsigned short*)(ws + 50 * MB);
    unsigned short* Wvb = (unsigned short*)(ws + 52 * MB);
    unsigned short* Wob = (unsigned short*)(ws + 54 * MB);
    unsigned short* AO  = Xq;   // attn output aliases Xq

    CvtArgs ca;
    ca.src[0] = q;  ca.dst[0] = Xq;  ca.n8[0] = (NB * S_LEN * DM) / 8;
    ca.src[1] = k;  ca.dst[1] = Xk;  ca.n8[1] = (NB * S_LEN * DM) / 8;
    ca.src[2] = v;  ca.dst[2] = Xv;  ca.n8[2] = (NB * S_LEN * DM) / 8;
    ca.src[3] = Wq; ca.dst[3] = Wqb; ca.n8[3] = (DM * DM) / 8;
    ca.src[4] = Wk; ca.dst[4] = Wkb; ca.n8[4] = (DM * DM) / 8;
    ca.src[5] = Wv; ca.dst[5] = Wvb; ca.n8[5] = (DM * DM) / 8;
    ca.src[6] = Wo; ca.dst[6] = Wob; ca.n8[6] = (DM * DM) / 8;
    cvt_f32_bf16<<<dim3(1024, 7), 256, 0, stream>>>(ca);

    gemm_qkv8<<<dim3(DM / 256, (NB * S_LEN) / 256, 3), 512, 0, stream>>>(
        Xq, Xk, Xv, Wqb, Wkb, Wvb, bq, bk, bv, Qb, Kb, Vt);

    attn_kernel<<<dim3(S_LEN / 128, NB * NH), 256, 0, stream>>>(Qb, Kb, Vt, AO);

    gemm_out<<<dim3(DM / 128, (NB * S_LEN) / 128), 256, 0, stream>>>(
        AO, Wob, bo, (float*)d_out);
}

// Round 4
// 132.842 us; speedup vs baseline: 1.0084x; 1.0084x over previous
//
#include <hip/hip_runtime.h>
#include <stdint.h>

#define S_LEN 2048
#define NB 2
#define NH 16
#define DK 64
#define DM 1024
#define QK_SCALE 0.125f
#define NEG_BIG -1e30f

typedef __attribute__((ext_vector_type(8))) short bf16x8;
typedef __attribute__((ext_vector_type(4))) float f32x4;

static __device__ __forceinline__ f32x4 mfma16(bf16x8 a, bf16x8 b, f32x4 c) {
    return __builtin_amdgcn_mfma_f32_16x16x32_bf16(a, b, c, 0, 0, 0);
}

// async global->LDS, 16B per lane; dst is wave-uniform base, HW adds lane*16
static __device__ __forceinline__ void gload_lds16(const void* g, void* l) {
    __builtin_amdgcn_global_load_lds((const __attribute__((address_space(1))) void*)g,
                                     (__attribute__((address_space(3))) void*)l,
                                     16, 0, 0);
}

// fp32 -> bf16 bits, RNE (inputs always finite here)
static __device__ __forceinline__ unsigned short f2bf(float x) {
    unsigned int u = __float_as_uint(x);
    u += 0x7fffu + ((u >> 16) & 1u);
    return (unsigned short)(u >> 16);
}

// ---------------- conversion: fp32 -> bf16, 7 tensors in one launch -------
struct CvtArgs {
    const float* src[7];
    unsigned short* dst[7];
    int n8[7];
};

__global__ __launch_bounds__(256) void cvt_f32_bf16(CvtArgs a) {
    const int t = blockIdx.y;
    const float* __restrict__ src = a.src[t];
    unsigned short* __restrict__ dst = a.dst[t];
    const int n8 = a.n8[t];
    const int stride = gridDim.x * blockDim.x;
    for (int i = blockIdx.x * blockDim.x + threadIdx.x; i < n8; i += stride) {
        float4 v0 = ((const float4*)src)[(size_t)i * 2];
        float4 v1 = ((const float4*)src)[(size_t)i * 2 + 1];
        union { bf16x8 v; unsigned short h[8]; } u;
        u.h[0] = f2bf(v0.x); u.h[1] = f2bf(v0.y); u.h[2] = f2bf(v0.z); u.h[3] = f2bf(v0.w);
        u.h[4] = f2bf(v1.x); u.h[5] = f2bf(v1.y); u.h[6] = f2bf(v1.z); u.h[7] = f2bf(v1.w);
        ((bf16x8*)dst)[i] = u.v;
    }
}

// ================= 256x256 8-phase QKV GEMM (T2+T3+T4+T5) ==================
// 512 threads = 8 waves (2M x 4N). Per-wave output 128x64 = acc[8][4].
// LDS 128KB: [A0 32K][B0 32K][A1 32K][B1 32K], double-buffered per K-tile(64).
// T2: chunk^=(row&7) involution; pre-swizzled GLOBAL src + swizzled ds_read.
// T4: counted vmcnt — at tile top, ISSUE P(t+1) first, then vmcnt(8) (waits
// only the 8 older P(t) loads; the new 8 stay in flight), then raw s_barrier.
// No __syncthreads in the loop => no vmcnt(0) drain in steady state.
__global__ __launch_bounds__(512, 2) void gemm_qkv8(
    const unsigned short* __restrict__ Xq, const unsigned short* __restrict__ Xk,
    const unsigned short* __restrict__ Xv,
    const unsigned short* __restrict__ Wq, const unsigned short* __restrict__ Wk,
    const unsigned short* __restrict__ Wv,
    const float* __restrict__ bq, const float* __restrict__ bk, const float* __restrict__ bv,
    unsigned short* __restrict__ Qo, unsigned short* __restrict__ Ko,
    unsigned short* __restrict__ Vt)
{
    __shared__ unsigned short lds[65536];   // 128 KiB

    const int tid = threadIdx.x, wid = tid >> 6, lane = tid & 63;
    const int wm = wid >> 2, wn = wid & 3;
    const int fr = lane & 15, fg = lane >> 4;
    const int z = blockIdx.z;
    const int m0 = blockIdx.y * 256, n0 = blockIdx.x * 256;

    const unsigned short* A = (z == 0) ? Xq : ((z == 1) ? Xk : Xv);
    const unsigned short* W = (z == 0) ? Wq : ((z == 1) ? Wk : Wv);
    const float* bias = (z == 0) ? bq : ((z == 1) ? bk : bv);

    // staging addressing (identical to round 3; PMC-verified conflict-free)
    const int srow = wid * 8 + (lane >> 3);
    const int scol = ((lane & 7) ^ (lane >> 3)) * 8;
    const unsigned short* pA = A + (size_t)(m0 + srow) * DM + scol;
    const unsigned short* pW = W + (size_t)(n0 + srow) * DM + scol;

    const int base_a = (wm * 128 + fr) * 64;
    const int base_b = (wn * 64 + fr) * 64;
    const int ck0 = ((0 * 4 + fg) ^ (fr & 7)) * 8;
    const int ck1 = ((1 * 4 + fg) ^ (fr & 7)) * 8;

    f32x4 acc[8][4] = {};

    // prologue: issue P(0) into buf0 (8 gload_lds/wave), no wait yet
    {
        unsigned short* dA = lds + wid * 512;
        unsigned short* dB = lds + 16384 + wid * 512;
        #pragma unroll
        for (int i = 0; i < 4; ++i) {
            gload_lds16(pA + (size_t)i * 64 * DM, dA + i * 4096);
            gload_lds16(pW + (size_t)i * 64 * DM, dB + i * 4096);
        }
    }

    for (int t = 0; t < 16; ++t) {
        const int c = t & 1;
        // issue P(t+1) into buf c^1 FIRST (WAR safe: all reads of c^1 finished
        // before the phase-2 post-barrier of tile t-1), then counted wait.
        if (t + 1 < 16) {
            const int k0 = (t + 1) * 64;
            unsigned short* dA = lds + (c ^ 1) * 32768 + wid * 512;
            unsigned short* dB = lds + (c ^ 1) * 32768 + 16384 + wid * 512;
            #pragma unroll
            for (int i = 0; i < 4; ++i) {
                gload_lds16(pA + (size_t)i * 64 * DM + k0, dA + i * 4096);
                gload_lds16(pW + (size_t)i * 64 * DM + k0, dB + i * 4096);
            }
            asm volatile("s_waitcnt vmcnt(8)" ::: "memory");  // P(t) landed, P(t+1) flying
        } else {
            asm volatile("s_waitcnt vmcnt(0)" ::: "memory");  // last tile: drain
        }
        __builtin_amdgcn_s_barrier();  // publish all waves' staging of buf c

        const unsigned short* sA = lds + c * 32768;
        const unsigned short* sB = sA + 16384;

        bf16x8 a0, a1, a2, a3, a0k, a1k, a2k, a3k;
        bf16x8 b0, b1, b2, b3, b0k, b1k, b2k, b3k;

        // ---- phase 0: A mf0-3 (both ksteps) + B nf0-1; MFMA m0-3 x n0-1
        a0  = *(const bf16x8*)(sA + base_a + 0 * 1024 + ck0);
        a1  = *(const bf16x8*)(sA + base_a + 1 * 1024 + ck0);
        a2  = *(const bf16x8*)(sA + base_a + 2 * 1024 + ck0);
        a3  = *(const bf16x8*)(sA + base_a + 3 * 1024 + ck0);
        a0k = *(const bf16x8*)(sA + base_a + 0 * 1024 + ck1);
        a1k = *(const bf16x8*)(sA + base_a + 1 * 1024 + ck1);
        a2k = *(const bf16x8*)(sA + base_a + 2 * 1024 + ck1);
        a3k = *(const bf16x8*)(sA + base_a + 3 * 1024 + ck1);
        b0  = *(const bf16x8*)(sB + base_b + 0 * 1024 + ck0);
        b1  = *(const bf16x8*)(sB + base_b + 1 * 1024 + ck0);
        b0k = *(const bf16x8*)(sB + base_b + 0 * 1024 + ck1);
        b1k = *(const bf16x8*)(sB + base_b + 1 * 1024 + ck1);
        __builtin_amdgcn_s_barrier();
        __builtin_amdgcn_s_setprio(1);
        acc[0][0] = mfma16(a0, b0, acc[0][0]); acc[0][0] = mfma16(a0k, b0k, acc[0][0]);
        acc[0][1] = mfma16(a0, b1, acc[0][1]); acc[0][1] = mfma16(a0k, b1k, acc[0][1]);
        acc[1][0] = mfma16(a1, b0, acc[1][0]); acc[1][0] = mfma16(a1k, b0k, acc[1][0]);
        acc[1][1] = mfma16(a1, b1, acc[1][1]); acc[1][1] = mfma16(a1k, b1k, acc[1][1]);
        acc[2][0] = mfma16(a2, b0, acc[2][0]); acc[2][0] = mfma16(a2k, b0k, acc[2][0]);
        acc[2][1] = mfma16(a2, b1, acc[2][1]); acc[2][1] = mfma16(a2k, b1k, acc[2][1]);
        acc[3][0] = mfma16(a3, b0, acc[3][0]); acc[3][0] = mfma16(a3k, b0k, acc[3][0]);
        acc[3][1] = mfma16(a3, b1, acc[3][1]); acc[3][1] = mfma16(a3k, b1k, acc[3][1]);
        __builtin_amdgcn_s_setprio(0);
        __builtin_amdgcn_s_barrier();

        // ---- phase 1: B nf2-3; MFMA m0-3 x n2-3
        b2  = *(const bf16x8*)(sB + base_b + 2 * 1024 + ck0);
        b3  = *(const bf16x8*)(sB + base_b + 3 * 1024 + ck0);
        b2k = *(const bf16x8*)(sB + base_b + 2 * 1024 + ck1);
        b3k = *(const bf16x8*)(sB + base_b + 3 * 1024 + ck1);
        __builtin_amdgcn_s_barrier();
        __builtin_amdgcn_s_setprio(1);
        acc[0][2] = mfma16(a0, b2, acc[0][2]); acc[0][2] = mfma16(a0k, b2k, acc[0][2]);
        acc[0][3] = mfma16(a0, b3, acc[0][3]); acc[0][3] = mfma16(a0k, b3k, acc[0][3]);
        acc[1][2] = mfma16(a1, b2, acc[1][2]); acc[1][2] = mfma16(a1k, b2k, acc[1][2]);
        acc[1][3] = mfma16(a1, b3, acc[1][3]); acc[1][3] = mfma16(a1k, b3k, acc[1][3]);
        acc[2][2] = mfma16(a2, b2, acc[2][2]); acc[2][2] = mfma16(a2k, b2k, acc[2][2]);
        acc[2][3] = mfma16(a2, b3, acc[2][3]); acc[2][3] = mfma16(a2k, b3k, acc[2][3]);
        acc[3][2] = mfma16(a3, b2, acc[3][2]); acc[3][2] = mfma16(a3k, b2k, acc[3][2]);
        acc[3][3] = mfma16(a3, b3, acc[3][3]); acc[3][3] = mfma16(a3k, b3k, acc[3][3]);
        __builtin_amdgcn_s_setprio(0);
        __builtin_amdgcn_s_barrier();

        // ---- phase 2: A mf4-7; MFMA m4-7 x n0-1
        a0  = *(const bf16x8*)(sA + base_a + 4 * 1024 + ck0);
        a1  = *(const bf16x8*)(sA + base_a + 5 * 1024 + ck0);
        a2  = *(const bf16x8*)(sA + base_a + 6 * 1024 + ck0);
        a3  = *(const bf16x8*)(sA + base_a + 7 * 1024 + ck0);
        a0k = *(const bf16x8*)(sA + base_a + 4 * 1024 + ck1);
        a1k = *(const bf16x8*)(sA + base_a + 5 * 1024 + ck1);
        a2k = *(const bf16x8*)(sA + base_a + 6 * 1024 + ck1);
        a3k = *(const bf16x8*)(sA + base_a + 7 * 1024 + ck1);
        __builtin_amdgcn_s_barrier();
        __builtin_amdgcn_s_setprio(1);
        acc[4][0] = mfma16(a0, b0, acc[4][0]); acc[4][0] = mfma16(a0k, b0k, acc[4][0]);
        acc[4][1] = mfma16(a0, b1, acc[4][1]); acc[4][1] = mfma16(a0k, b1k, acc[4][1]);
        acc[5][0] = mfma16(a1, b0, acc[5][0]); acc[5][0] = mfma16(a1k, b0k, acc[5][0]);
        acc[5][1] = mfma16(a1, b1, acc[5][1]); acc[5][1] = mfma16(a1k, b1k, acc[5][1]);
        acc[6][0] = mfma16(a2, b0, acc[6][0]); acc[6][0] = mfma16(a2k, b0k, acc[6][0]);
        acc[6][1] = mfma16(a2, b1, acc[6][1]); acc[6][1] = mfma16(a2k, b1k, acc[6][1]);
        acc[7][0] = mfma16(a3, b0, acc[7][0]); acc[7][0] = mfma16(a3k, b0k, acc[7][0]);
        acc[7][1] = mfma16(a3, b1, acc[7][1]); acc[7][1] = mfma16(a3k, b1k, acc[7][1]);
        __builtin_amdgcn_s_setprio(0);
        __builtin_amdgcn_s_barrier();

        // ---- phase 3: MFMA m4-7 x n2-3 (no loads, no trailing drain)
        __builtin_amdgcn_s_setprio(1);
        acc[4][2] = mfma16(a0, b2, acc[4][2]); acc[4][2] = mfma16(a0k, b2k, acc[4][2]);
        acc[4][3] = mfma16(a0, b3, acc[4][3]); acc[4][3] = mfma16(a0k, b3k, acc[4][3]);
        acc[5][2] = mfma16(a1, b2, acc[5][2]); acc[5][2] = mfma16(a1k, b2k, acc[5][2]);
        acc[5][3] = mfma16(a1, b3, acc[5][3]); acc[5][3] = mfma16(a1k, b3k, acc[5][3]);
        acc[6][2] = mfma16(a2, b2, acc[6][2]); acc[6][2] = mfma16(a2k, b2k, acc[6][2]);
        acc[6][3] = mfma16(a2, b3, acc[6][3]); acc[6][3] = mfma16(a2k, b3k, acc[6][3]);
        acc[7][2] = mfma16(a3, b2, acc[7][2]); acc[7][2] = mfma16(a3k, b2k, acc[7][2]);
        acc[7][3] = mfma16(a3, b3, acc[7][3]); acc[7][3] = mfma16(a3k, b3k, acc[7][3]);
        __builtin_amdgcn_s_setprio(0);
    }

    // epilogue (acc registers only; no LDS reuse after loop)
    unsigned short* Ohw = (z == 0) ? Qo : Ko;
    #pragma unroll
    for (int nf = 0; nf < 4; ++nf) {
        const int col = n0 + wn * 64 + nf * 16 + fr;
        const float bb = bias[col];
        const int h = col >> 6, dd = col & (DK - 1);
        #pragma unroll
        for (int mf = 0; mf < 8; ++mf) {
            #pragma unroll
            for (int r = 0; r < 4; ++r) {
                const int row = m0 + wm * 128 + mf * 16 + fg * 4 + r;
                const int b = row >> 11, s = row & (S_LEN - 1);
                const float val = acc[mf][nf][r] + bb;
                if (z < 2)
                    Ohw[(((size_t)b * NH + h) * S_LEN + s) * DK + dd] = f2bf(val);
                else
                    Vt[(((size_t)b * NH + h) * DK + dd) * S_LEN + s] = f2bf(val);
            }
        }
    }
}

// ---------------- GEMM core (m97 128^2) for the output projection ----------
static __device__ __forceinline__ void gemm_core_128(
    const unsigned short* __restrict__ A,
    const unsigned short* __restrict__ W,
    unsigned short* sA, unsigned short* sB,
    int K, int m0, int n0, f32x4 acc[4][4])
{
    const int tid = threadIdx.x;
    const int wid = tid >> 6, lane = tid & 63;
    const int wr = wid >> 1, wc = wid & 1;
    const int fr = lane & 15, fg = lane >> 4;
    const int ldr = lane >> 3, ldc = (lane & 7) * 8;

    const unsigned short* pA = A + (size_t)(m0 + ldr) * K + ldc;
    const unsigned short* pW = W + (size_t)(n0 + ldr) * K + ldc;

    for (int k0 = 0; k0 < K; k0 += 64) {
        __syncthreads();
        #pragma unroll
        for (int it = 0; it < 4; ++it) {
            const int rb = wid * 32 + it * 8;
            gload_lds16(pA + (size_t)(rb)*K + k0, sA + rb * 64);
            gload_lds16(pW + (size_t)(rb)*K + k0, sB + rb * 64);
        }
        __syncthreads();
        #pragma unroll
        for (int kf = 0; kf < 2; ++kf) {
            bf16x8 af[4], bfr[4];
            #pragma unroll
            for (int mf = 0; mf < 4; ++mf)
                af[mf] = *(const bf16x8*)(sA + (wr * 64 + mf * 16 + fr) * 64 + kf * 32 + fg * 8);
            #pragma unroll
            for (int nf = 0; nf < 4; ++nf)
                bfr[nf] = *(const bf16x8*)(sB + (wc * 64 + nf * 16 + fr) * 64 + kf * 32 + fg * 8);
            #pragma unroll
            for (int mf = 0; mf < 4; ++mf)
                #pragma unroll
                for (int nf = 0; nf < 4; ++nf)
                    acc[mf][nf] = mfma16(af[mf], bfr[nf], acc[mf][nf]);
        }
    }
}

// ---------------- final output projection: fp32 out + bias -----------------
__global__ __launch_bounds__(256, 2) void gemm_out(
    const unsigned short* __restrict__ A, const unsigned short* __restrict__ W,
    const float* __restrict__ bias, float* __restrict__ out)
{
    __shared__ unsigned short sA[128 * 64];
    __shared__ unsigned short sB[128 * 64];
    const int m0 = blockIdx.y * 128, n0 = blockIdx.x * 128;
    f32x4 acc[4][4] = {};
    gemm_core_128(A, W, sA, sB, DM, m0, n0, acc);
    const int tid = threadIdx.x, wid = tid >> 6, lane = tid & 63;
    const int wr = wid >> 1, wc = wid & 1, fr = lane & 15, fg = lane >> 4;
    #pragma unroll
    for (int nf = 0; nf < 4; ++nf) {
        const int col = n0 + wc * 64 + nf * 16 + fr;
        const float bb = bias[col];
        #pragma unroll
        for (int mf = 0; mf < 4; ++mf) {
            #pragma unroll
            for (int r = 0; r < 4; ++r) {
                const int row = m0 + wr * 64 + mf * 16 + fg * 4 + r;
                out[(size_t)row * DM + col] = acc[mf][nf][r] + bb;
            }
        }
    }
}

// ---------------- banded flash attention ----------------------------------
__global__ __launch_bounds__(256, 2) void attn_kernel(
    const unsigned short* __restrict__ Qb,   // [B,H,S,64]
    const unsigned short* __restrict__ Kb,   // [B,H,S,64]
    const unsigned short* __restrict__ Vt,   // [B,H,64,S]
    unsigned short* __restrict__ Oout)       // [B*S, 1024] token-major
{
    __shared__ unsigned short sK[128 * 64];
    __shared__ unsigned short sV[64 * 128];
    __shared__ unsigned short sP[4][32 * 128];

    const int tid = threadIdx.x, wid = tid >> 6, lane = tid & 63;
    const int fr = lane & 15, fg = lane >> 4;
    const int qt = blockIdx.x, bh = blockIdx.y;
    const int q0 = qt * 128;
    const size_t base = (size_t)bh * (S_LEN * DK);

    bf16x8 qf[2][2];
    #pragma unroll
    for (int mf = 0; mf < 2; ++mf)
        #pragma unroll
        for (int kf = 0; kf < 2; ++kf)
            qf[mf][kf] = *(const bf16x8*)(Qb + base +
                (size_t)(q0 + wid * 32 + mf * 16 + fr) * DK + kf * 32 + fg * 8);

    f32x4 oacc[2][4] = {};
    float m_run[2][4], l_run[2][4];
    #pragma unroll
    for (int mf = 0; mf < 2; ++mf)
        #pragma unroll
        for (int r = 0; r < 4; ++r) { m_run[mf][r] = NEG_BIG; l_run[mf][r] = 0.f; }

    const int t_lo = (qt == 0) ? 1 : 0;
    const int t_hi = (qt == (S_LEN / 128 - 1)) ? 1 : 2;

    for (int t = t_lo; t <= t_hi; ++t) {
        const int kt0 = q0 + (t - 1) * 128;
        __syncthreads();
        {
            const unsigned short* gK = Kb + base + (size_t)kt0 * DK;
            #pragma unroll
            for (int it = 0; it < 4; ++it) {
                const int chunk = wid * 4 + it;
                gload_lds16(gK + chunk * 512 + lane * 8, sK + chunk * 512);
            }
            const unsigned short* gV = Vt + base + kt0;
            #pragma unroll
            for (int it = 0; it < 4; ++it) {
                const int chunk = wid * 4 + it;
                gload_lds16(gV + (size_t)(chunk * 4 + fg) * S_LEN + fr * 8, sV + chunk * 512);
            }
        }
        __syncthreads();

        f32x4 sacc[2][8] = {};
        #pragma unroll
        for (int kf = 0; kf < 2; ++kf) {
            bf16x8 kfr[8];
            #pragma unroll
            for (int nf = 0; nf < 8; ++nf)
                kfr[nf] = *(const bf16x8*)(sK + (nf * 16 + fr) * 64 + kf * 32 + fg * 8);
            #pragma unroll
            for (int mf = 0; mf < 2; ++mf)
                #pragma unroll
                for (int nf = 0; nf < 8; ++nf)
                    sacc[mf][nf] = mfma16(qf[mf][kf], kfr[nf], sacc[mf][nf]);
        }

        const int dt = (t - 1) * 128;
        #pragma unroll
        for (int mf = 0; mf < 2; ++mf) {
            #pragma unroll
            for (int r = 0; r < 4; ++r) {
                const int row = wid * 32 + mf * 16 + fg * 4 + r;
                float mm = NEG_BIG;
                #pragma unroll
                for (int nf = 0; nf < 8; ++nf) {
                    const int col = nf * 16 + fr;
                    const int diff = dt + col - row;
                    float s = sacc[mf][nf][r] * QK_SCALE;
                    s = (diff >= -128 && diff < 128) ? s : NEG_BIG;
                    sacc[mf][nf][r] = s;
                    mm = fmaxf(mm, s);
                }
                #pragma unroll
                for (int d = 1; d < 16; d <<= 1) mm = fmaxf(mm, __shfl_xor(mm, d));
                const float mold = m_run[mf][r];
                const float mn = fmaxf(mold, mm);
                m_run[mf][r] = mn;
                const float alpha = __expf(mold - mn);
                float ps = 0.f;
                #pragma unroll
                for (int nf = 0; nf < 8; ++nf) {
                    const float p = __expf(sacc[mf][nf][r] - mn);
                    ps += p;
                    sP[wid][(mf * 16 + fg * 4 + r) * 128 + nf * 16 + fr] = f2bf(p);
                }
                #pragma unroll
                for (int d = 1; d < 16; d <<= 1) ps += __shfl_xor(ps, d);
                l_run[mf][r] = l_run[mf][r] * alpha + ps;
                #pragma unroll
                for (int nf = 0; nf < 4; ++nf)
                    oacc[mf][nf][r] = oacc[mf][nf][r] * alpha;
            }
        }

        #pragma unroll
        for (int kf = 0; kf < 4; ++kf) {
            bf16x8 pa[2], vb[4];
            #pragma unroll
            for (int mf = 0; mf < 2; ++mf)
                pa[mf] = *(const bf16x8*)(&sP[wid][(mf * 16 + fr) * 128 + kf * 32 + fg * 8]);
            #pragma unroll
            for (int nf = 0; nf < 4; ++nf)
                vb[nf] = *(const bf16x8*)(sV + (nf * 16 + fr) * 128 + kf * 32 + fg * 8);
            #pragma unroll
            for (int mf = 0; mf < 2; ++mf)
                #pragma unroll
                for (int nf = 0; nf < 4; ++nf)
                    oacc[mf][nf] = mfma16(pa[mf], vb[nf], oacc[mf][nf]);
        }
    }

    const int b = bh >> 4, h = bh & 15;
    #pragma unroll
    for (int mf = 0; mf < 2; ++mf) {
        #pragma unroll
        for (int r = 0; r < 4; ++r) {
            const float inv = 1.0f / l_run[mf][r];
            const int token = b * S_LEN + q0 + wid * 32 + mf * 16 + fg * 4 + r;
            #pragma unroll
            for (int nf = 0; nf < 4; ++nf) {
                const int feat = h * 64 + nf * 16 + fr;
                Oout[(size_t)token * DM + feat] = f2bf(oacc[mf][nf][r] * inv);
            }
        }
    }
}

// ---------------------------------------------------------------------------
extern "C" void kernel_launch(void* const* d_in, const int* in_sizes, int n_in,
                              void* d_out, int out_size, void* d_ws, size_t ws_size,
                              hipStream_t stream)
{
    (void)in_sizes; (void)n_in; (void)out_size; (void)ws_size;
    const float* q  = (const float*)d_in[0];
    const float* k  = (const float*)d_in[1];
    const float* v  = (const float*)d_in[2];
    const float* Wq = (const float*)d_in[3];
    const float* bq = (const float*)d_in[4];
    const float* Wk = (const float*)d_in[5];
    const float* bk = (const float*)d_in[6];
    const float* Wv = (const float*)d_in[7];
    const float* bv = (const float*)d_in[8];
    const float* Wo = (const float*)d_in[9];
    const float* bo = (const float*)d_in[10];

    char* ws = (char*)d_ws;
    const size_t MB = 1024 * 1024;
    unsigned short* Xq  = (unsigned short*)(ws + 0 * MB);
    unsigned short* Xk  = (unsigned short*)(ws + 8 * MB);
    unsigned short* Xv  = (unsigned short*)(ws + 16 * MB);
    unsigned short* Qb  = (unsigned short*)(ws + 24 * MB);
    unsigned short* Kb  = (unsigned short*)(ws + 32 * MB);
    unsigned short* Vt  = (unsigned short*)(ws + 40 * MB);
    unsigned short* Wqb = (unsigned short*)(ws + 48 * MB);
    unsigned short* Wkb = (unsigned short*)(ws + 50 * MB);
    unsigned short* Wvb = (unsigned short*)(ws + 52 * MB);
    unsigned short* Wob = (unsigned short*)(ws + 54 * MB);
    unsigned short* AO  = Xq;   // attn output aliases Xq

    CvtArgs ca;
    ca.src[0] = q;  ca.dst[0] = Xq;  ca.n8[0] = (NB * S_LEN * DM) / 8;
    ca.src[1] = k;  ca.dst[1] = Xk;  ca.n8[1] = (NB * S_LEN * DM) / 8;
    ca.src[2] = v;  ca.dst[2] = Xv;  ca.n8[2] = (NB * S_LEN * DM) / 8;
    ca.src[3] = Wq; ca.dst[3] = Wqb; ca.n8[3] = (DM * DM) / 8;
    ca.src[4] = Wk; ca.dst[4] = Wkb; ca.n8[4] = (DM * DM) / 8;
    ca.src[5] = Wv; ca.dst[5] = Wvb; ca.n8[5] = (DM * DM) / 8;
    ca.src[6] = Wo; ca.dst[6] = Wob; ca.n8[6] = (DM * DM) / 8;
    cvt_f32_bf16<<<dim3(1024, 7), 256, 0, stream>>>(ca);

    gemm_qkv8<<<dim3(DM / 256, (NB * S_LEN) / 256, 3), 512, 0, stream>>>(
        Xq, Xk, Xv, Wqb, Wkb, Wvb, bq, bk, bv, Qb, Kb, Vt);

    attn_kernel<<<dim3(S_LEN / 128, NB * NH), 256, 0, stream>>>(Qb, Kb, Vt, AO);

    gemm_out<<<dim3(DM / 128, (NB * S_LEN) / 128), 256, 0, stream>>>(
        AO, Wob, bo, (float*)d_out);
}